// Round 1
// baseline (185.553 us; speedup 1.0000x reference)
//
#include <hip/hip_runtime.h>

// Problem constants (fixed by the reference's setup_inputs).
constexpr int N = 8192;          // row length
constexpr int K = 64;            // top-k
constexpr int THREADS = 256;
constexpr int EPT = N / THREADS; // 32 elements per thread
constexpr int HIST_BINS = 2048;  // 11-bit rounds

// Map fp32 bits to an unsigned key with the same total order as float.
__device__ __forceinline__ unsigned orderable(float f) {
    unsigned x = __float_as_uint(f);
    return (x & 0x80000000u) ? ~x : (x | 0x80000000u);
}

__global__ __launch_bounds__(THREADS)
void gumbel_topk_onehot(const float* __restrict__ logits,
                        const float* __restrict__ noise,
                        float* __restrict__ out)
{
    __shared__ unsigned u_sh[N];          // 32 KB: orderable keys for the row
    __shared__ unsigned hist[HIST_BINS];  // 8 KB histogram
    __shared__ unsigned part[THREADS];    // scan buffer
    __shared__ unsigned sel_prefix, sel_kth, sel_cnt;

    const int tid = threadIdx.x;
    const long long row = blockIdx.x;
    const float4* lrow = (const float4*)(logits + row * (long long)N);
    const float4* nrow = (const float4*)(noise  + row * (long long)N);

    // ---- Load row, g = logits + noise, store orderable keys in LDS ----
#pragma unroll
    for (int i = 0; i < EPT / 4; ++i) {
        int idx = tid + i * THREADS;   // float4 index, fully coalesced
        float4 a = lrow[idx];
        float4 b = nrow[idx];
        u_sh[4 * idx + 0] = orderable(a.x + b.x);
        u_sh[4 * idx + 1] = orderable(a.y + b.y);
        u_sh[4 * idx + 2] = orderable(a.z + b.z);
        u_sh[4 * idx + 3] = orderable(a.w + b.w);
    }

    // ---- Radix select: find T = key of the K-th largest element ----
    // Rounds over bit fields [31:21], [20:10], [9:0].
    unsigned prefix = 0;  // bits of T fixed so far
    unsigned kth = K;     // 1-based rank (from the top) within current candidates

#pragma unroll
    for (int r = 0; r < 3; ++r) {
        const int shift = (r == 0) ? 21 : (r == 1) ? 10 : 0;
        const int bits  = (r == 2) ? 10 : 11;
        const unsigned nb = 1u << bits;

        __syncthreads();   // protects u_sh (r=0) / prev round's hist reads
        for (int i = tid; i < HIST_BINS; i += THREADS) hist[i] = 0;
        __syncthreads();

        for (int i = tid; i < N; i += THREADS) {
            unsigned u = u_sh[i];
            bool match = (r == 0) ? true : ((u >> (shift + bits)) == prefix);
            if (match) atomicAdd(&hist[(u >> shift) & (nb - 1u)], 1u);
        }
        __syncthreads();

        // Per-thread partial sums over its contiguous bin range.
        const int bpt = nb / THREADS;   // 8 (11-bit) or 4 (10-bit)
        unsigned p = 0;
#pragma unroll
        for (int j = 0; j < 8; ++j)
            if (j < bpt) p += hist[tid * bpt + j];
        part[tid] = p;
        __syncthreads();

        // Inclusive suffix scan: part[t] = count of candidates in bins >= t*bpt.
        for (int off = 1; off < THREADS; off <<= 1) {
            unsigned v = (tid + off < THREADS) ? part[tid + off] : 0u;
            __syncthreads();
            part[tid] += v;
            __syncthreads();
        }

        unsigned snext = (tid + 1 < THREADS) ? part[tid + 1] : 0u;
        if (part[tid] >= kth && snext < kth) {
            // The target bin lies in this thread's range; walk it high->low.
            unsigned cum = snext;  // candidates in bins above this range
            for (int j = bpt - 1; j >= 0; --j) {
                unsigned c = hist[tid * bpt + j];
                if (cum + c >= kth) {
                    sel_prefix = (prefix << bits) | (unsigned)(tid * bpt + j);
                    sel_kth = kth - cum;   // rank within the selected bin
                    sel_cnt = c;           // candidate count in the selected bin
                    break;
                }
                cum += c;
            }
        }
        __syncthreads();
        prefix = sel_prefix;
        kth = sel_kth;
    }

    const unsigned T = prefix;        // exact bit pattern of the K-th largest
    const unsigned take_eq = kth;     // how many ==T elements belong to top-K
    const unsigned c_eq = sel_cnt;    // total elements ==T
    const bool fastpath = (take_eq == c_eq);  // no boundary-straddling tie

    // ---- Write one-hot output ----
    float4* orow = (float4*)(out + row * (long long)N);
#pragma unroll
    for (int i = 0; i < EPT / 4; ++i) {
        int idx = tid + i * THREADS;
        unsigned u0 = u_sh[4 * idx + 0];
        unsigned u1 = u_sh[4 * idx + 1];
        unsigned u2 = u_sh[4 * idx + 2];
        unsigned u3 = u_sh[4 * idx + 3];
        float4 o;
        o.x = (u0 > T || (fastpath && u0 == T)) ? 1.0f : 0.0f;
        o.y = (u1 > T || (fastpath && u1 == T)) ? 1.0f : 0.0f;
        o.z = (u2 > T || (fastpath && u2 == T)) ? 1.0f : 0.0f;
        o.w = (u3 > T || (fastpath && u3 == T)) ? 1.0f : 0.0f;
        orow[idx] = o;
    }

    // Rare path: tie group straddles the rank-64 boundary. Reference
    // (jax.lax.top_k) takes the LOWEST indices among equal values.
    if (!fastpath) {
        __syncthreads();   // drain the zero-writes above before fix-up
        if (tid == 0) {
            unsigned c = 0;
            float* orowf = out + row * (long long)N;
            for (int i = 0; i < N; ++i) {
                if (u_sh[i] == T) {
                    orowf[i] = 1.0f;
                    if (++c == take_eq) break;
                }
            }
        }
    }
}

extern "C" void kernel_launch(void* const* d_in, const int* in_sizes, int n_in,
                              void* d_out, int out_size, void* d_ws, size_t ws_size,
                              hipStream_t stream) {
    const float* logits = (const float*)d_in[0];
    const float* noise  = (const float*)d_in[1];
    float* out = (float*)d_out;
    const int rows = in_sizes[0] / N;   // 2048
    gumbel_topk_onehot<<<rows, THREADS, 0, stream>>>(logits, noise, out);
}

// Round 2
// 172.043 us; speedup vs baseline: 1.0785x; 1.0785x over previous
//
#include <hip/hip_runtime.h>

// Problem constants (fixed by the reference's setup_inputs).
constexpr int N = 8192;          // row length
constexpr int K = 64;            // top-k
constexpr int THREADS = 256;
constexpr int WAVES = THREADS / 64;
constexpr int EPT = N / THREADS; // 32 elements per thread (in registers)
constexpr int VEC = EPT / 4;     // 8 float4 loads per thread
constexpr int CAP = 3072;        // candidate buffer capacity (12 KB)

// Map fp32 bits to an unsigned key with the same total order as float.
__device__ __forceinline__ unsigned orderable(float f) {
    unsigned x = __float_as_uint(f);
    return (x & 0x80000000u) ? ~x : (x | 0x80000000u);
}

__global__ __launch_bounds__(THREADS, 4)
void gumbel_topk_onehot(const float* __restrict__ logits,
                        const float* __restrict__ noise,
                        float* __restrict__ out)
{
    __shared__ unsigned hist[2048];      // 8 KB
    __shared__ unsigned cand[CAP];       // 12 KB: low-21-bit keys of round-1 survivors
    __shared__ unsigned wavesum[WAVES];
    __shared__ unsigned ccount;
    __shared__ unsigned sel_bin, sel_kth, sel_cnt;

    const int tid  = threadIdx.x;
    const int lane = tid & 63;
    const int wave = tid >> 6;
    const long long row = blockIdx.x;

    const float4* lrow = (const float4*)(logits + row * (long long)N);
    const float4* nrow = (const float4*)(noise  + row * (long long)N);

    // ---- Load row; keep orderable keys in REGISTERS (no 32KB LDS row) ----
    unsigned key[EPT];
#pragma unroll
    for (int i = 0; i < VEC; ++i) {
        int idx = tid + i * THREADS;     // float4 index, coalesced
        float4 a = lrow[idx];
        float4 b = nrow[idx];
        key[4*i+0] = orderable(a.x + b.x);
        key[4*i+1] = orderable(a.y + b.y);
        key[4*i+2] = orderable(a.z + b.z);
        key[4*i+3] = orderable(a.w + b.w);
    }

    // ======== Round 1: histogram over bits [31:21] (2048 bins) ========
    {
        uint4 z = make_uint4(0,0,0,0);
        for (int i = tid; i < 512; i += THREADS) ((uint4*)hist)[i] = z;
    }
    if (tid == 0) ccount = 0;
    __syncthreads();
#pragma unroll
    for (int e = 0; e < EPT; ++e)
        atomicAdd(&hist[key[e] >> 21], 1u);
    __syncthreads();

    unsigned kth = K;

    // suffix scan + bin selection (macro-ish inline, bpt = bins per thread)
#define SELECT_BIN(BPT)                                                      \
    {                                                                        \
        unsigned p = 0;                                                      \
        _Pragma("unroll")                                                    \
        for (int j = 0; j < (BPT); ++j) p += hist[tid * (BPT) + j];          \
        unsigned s = p;                                                      \
        _Pragma("unroll")                                                    \
        for (int off = 1; off < 64; off <<= 1) {                             \
            unsigned v = __shfl_down(s, off);                                \
            if (lane + off < 64) s += v;                                     \
        }                                                                    \
        if (lane == 0) wavesum[wave] = s;                                    \
        __syncthreads();                                                     \
        unsigned S = s;                                                      \
        _Pragma("unroll")                                                    \
        for (int w = 0; w < WAVES; ++w) if (w > wave) S += wavesum[w];       \
        unsigned Snext = S - p;                                              \
        if (S >= kth && Snext < kth) {                                       \
            unsigned cum = Snext;                                            \
            for (int j = (BPT) - 1; j >= 0; --j) {                           \
                unsigned c = hist[tid * (BPT) + j];                          \
                if (cum + c >= kth) {                                        \
                    sel_bin = (unsigned)(tid * (BPT) + j);                   \
                    sel_kth = kth - cum;                                     \
                    sel_cnt = c;                                             \
                    break;                                                   \
                }                                                            \
                cum += c;                                                    \
            }                                                                \
        }                                                                    \
        __syncthreads();                                                     \
    }

    SELECT_BIN(8)
    const unsigned b1   = sel_bin;   // winning 11-bit high field
    const unsigned cnt1 = sel_cnt;   // elements in that bin
    kth = sel_kth;                   // rank within the bin
    __syncthreads();                 // sel_* consumed before round 2 reuses them

    // ---- Compact round-1 survivors (low 21 bits) into small buffer ----
    const bool use_cand = (cnt1 <= (unsigned)CAP);
#pragma unroll
    for (int e = 0; e < EPT; ++e) {
        if ((key[e] >> 21) == b1) {
            unsigned pos = atomicAdd(&ccount, 1u);
            if (pos < (unsigned)CAP) cand[pos] = key[e] & 0x1FFFFFu;
        }
    }
    // barrier below (hist zero) also covers compaction completion

    // ======== Round 2: histogram over bits [20:10] (2048 bins) ========
    __syncthreads();
    {
        uint4 z = make_uint4(0,0,0,0);
        for (int i = tid; i < 512; i += THREADS) ((uint4*)hist)[i] = z;
    }
    __syncthreads();
    if (use_cand) {
        for (int i = tid; i < (int)cnt1; i += THREADS)
            atomicAdd(&hist[cand[i] >> 10], 1u);
    } else {
#pragma unroll
        for (int e = 0; e < EPT; ++e)
            if ((key[e] >> 21) == b1)
                atomicAdd(&hist[(key[e] >> 10) & 0x7FFu], 1u);
    }
    __syncthreads();

    SELECT_BIN(8)
    const unsigned b2 = sel_bin;     // winning 11-bit mid field
    kth = sel_kth;
    __syncthreads();

    // ======== Round 3: histogram over bits [9:0] (1024 bins) ========
    {
        uint4 z = make_uint4(0,0,0,0);
        for (int i = tid; i < 256; i += THREADS) ((uint4*)hist)[i] = z;
    }
    __syncthreads();
    if (use_cand) {
        for (int i = tid; i < (int)cnt1; i += THREADS) {
            unsigned cv = cand[i];
            if ((cv >> 10) == b2) atomicAdd(&hist[cv & 0x3FFu], 1u);
        }
    } else {
        const unsigned pfx = (b1 << 11) | b2;
#pragma unroll
        for (int e = 0; e < EPT; ++e)
            if ((key[e] >> 10) == pfx)
                atomicAdd(&hist[key[e] & 0x3FFu], 1u);
    }
    __syncthreads();

    SELECT_BIN(4)
    const unsigned b3      = sel_bin;
    const unsigned take_eq = sel_kth;  // how many ==T values belong to top-K
    const unsigned c_eq    = sel_cnt;  // total ==T values

    const unsigned T = (b1 << 21) | (b2 << 10) | b3;  // exact K-th largest key
    const bool fast = (take_eq == c_eq);              // no boundary-straddling tie

    // ---- Write one-hot output from registers ----
    float4* orow = (float4*)(out + row * (long long)N);
#pragma unroll
    for (int i = 0; i < VEC; ++i) {
        int idx = tid + i * THREADS;
        float4 o;
        o.x = (key[4*i+0] > T || (fast && key[4*i+0] == T)) ? 1.0f : 0.0f;
        o.y = (key[4*i+1] > T || (fast && key[4*i+1] == T)) ? 1.0f : 0.0f;
        o.z = (key[4*i+2] > T || (fast && key[4*i+2] == T)) ? 1.0f : 0.0f;
        o.w = (key[4*i+3] > T || (fast && key[4*i+3] == T)) ? 1.0f : 0.0f;
        orow[idx] = o;
    }

    // Rare path: tie group straddles the boundary — lowest indices win
    // (jax.lax.top_k semantics). Recompute serially from global.
    if (!fast) {
        __syncthreads();   // compiler drains vmcnt before barrier -> stores done
        if (tid == 0) {
            const float* lf = logits + row * (long long)N;
            const float* nf = noise  + row * (long long)N;
            float* of = out + row * (long long)N;
            unsigned c = 0;
            for (int i = 0; i < N; ++i) {
                if (orderable(lf[i] + nf[i]) == T) {
                    of[i] = 1.0f;
                    if (++c == take_eq) break;
                }
            }
        }
    }
#undef SELECT_BIN
}

extern "C" void kernel_launch(void* const* d_in, const int* in_sizes, int n_in,
                              void* d_out, int out_size, void* d_ws, size_t ws_size,
                              hipStream_t stream) {
    const float* logits = (const float*)d_in[0];
    const float* noise  = (const float*)d_in[1];
    float* out = (float*)d_out;
    const int rows = in_sizes[0] / N;   // 2048
    gumbel_topk_onehot<<<rows, THREADS, 0, stream>>>(logits, noise, out);
}